// Round 7
// baseline (552.280 us; speedup 1.0000x reference)
//
#include <hip/hip_runtime.h>

#define T_STEPS 1024
#define BATCH 2048
#define BTILE 8   // 8 batch rows/block -> 256 blocks -> 1 block/CU
#define HS 36     // LDS row stride in u32 words; 36 % 32 == 4 -> conflict-free b128 reads

typedef short short8 __attribute__((ext_vector_type(8)));
typedef float f32x4 __attribute__((ext_vector_type(4)));
typedef float f32x2 __attribute__((ext_vector_type(2)));

__device__ __forceinline__ float fast_rcp(float x) {
#if __has_builtin(__builtin_amdgcn_rcpf)
    return __builtin_amdgcn_rcpf(x);
#else
    return 1.0f / x;
#endif
}

__device__ __forceinline__ float fast_exp2(float x) {
#if __has_builtin(__builtin_amdgcn_exp2f)
    return __builtin_amdgcn_exp2f(x);
#else
    return exp2f(x);
#endif
}

__device__ __forceinline__ float sigf(float x) {
    return fast_rcp(1.0f + fast_exp2(-1.44269504f * x));
}

__device__ __forceinline__ f32x2 sigf2(f32x2 v) {
    f32x2 t = v * (-1.44269504f);
    f32x2 e = {fast_exp2(t[0]), fast_exp2(t[1])};
    e = e + 1.0f;
    return f32x2{fast_rcp(e[0]), fast_rcp(e[1])};
}

__device__ __forceinline__ float tanh_fast(float x) {
    float e = fast_exp2(2.88539008f * x);
    return 1.0f - 2.0f * fast_rcp(e + 1.0f);
}

__device__ __forceinline__ f32x2 tanh2(f32x2 v) {
    f32x2 t = v * 2.88539008f;
    f32x2 e = {fast_exp2(t[0]), fast_exp2(t[1])};
    e = e + 1.0f;
    f32x2 r = {fast_rcp(e[0]), fast_rcp(e[1])};
    return f32x2{1.0f, 1.0f} - 2.0f * r;
}

// float -> bf16 bits (RNE) — setup only
__device__ __forceinline__ unsigned f2bf(float x) {
    unsigned u = __float_as_uint(x);
    unsigned r = u + 0x7FFFu + ((u >> 16) & 1u);
    return r >> 16;
}

__device__ __forceinline__ unsigned cvt_pk_bf16(float a, float b) {
    unsigned r;
    asm("v_cvt_pk_bf16_f32 %0, %1, %2" : "=v"(r) : "v"(a), "v"(b));
    return r;
}

// DPP: 0x128 = row_ror:8 — within each 16-lane row, lane l <- lane (l+8)%16
// = lane l^8. Same lane pairing as ds_swizzle xor8, but VALU-latency.
__device__ __forceinline__ float dpp_xor8(float v) {
    return __int_as_float(__builtin_amdgcn_update_dpp(0, __float_as_int(v), 0x128, 0xf, 0xf, true));
}

// Per-step barrier without the vmcnt(0) drain __syncthreads() emits.
// All in-loop cross-wave traffic is LDS (lgkmcnt(0)+s_barrier orders it);
// global ops are write-only stores / same-thread prefetch.
__device__ __forceinline__ void step_barrier() {
    asm volatile("s_waitcnt lgkmcnt(0)\n\ts_barrier" ::: "memory");
}

// ===================== v15: deferred L2 partial reduce ======================
// v14's barrier straggler: the xor8/xor16 ds_swizzle chain (~250cy LDS
// latency) hung off c0n2 on the critical path every step. v15 defers it:
// the 4 pre-reduce FMA results (pgc) stay in REGISTERS across the barrier,
// and the reduce+Pbuf-write runs at the TOP of the next iteration, hidden
// under that iteration's MFMA latency. xor8 is now a DPP row_ror:8 (VALU,
// same lane pairs, bit-identical sum order); only xor16 remains an LDS op.
// Wave 4 consumes partials with a 2-step lag (Pbuf parity = step&1; reads
// parity t&1, writes parity (t-1)&1 — always disjoint). Epilogue flushes
// steps 1022/1023.
__global__ __launch_bounds__(320, 1)
void lstm_v15_kernel(const float* __restrict__ input,
                     const float* __restrict__ W_ih0,
                     const float* __restrict__ W_hh0,
                     const float* __restrict__ b_ih0,
                     const float* __restrict__ b_hh0,
                     const float* __restrict__ W_ih1,
                     const float* __restrict__ W_hh1,
                     const float* __restrict__ b_ih1,
                     const float* __restrict__ b_hh1,
                     float* __restrict__ out)
{
    const int tid = threadIdx.x;
    const int w8  = tid >> 6;        // wave 0..3 = L1 compute, wave 4 = L2 recurrence
    const int l   = tid & 63;
    const int q16 = l >> 4;
    const int n16 = l & 15;
    const int n8  = l & 7;           // batch within block
    const int hi8 = n16 >> 3;
    const int ua  = 16 * w8 + 4 * q16 + 2 * hi8;   // even unit of thread's pair (w8<4)
    const int bbase = blockIdx.x * BTILE;

    __shared__ __align__(16) unsigned Hbuf[2][16][HS];   // h plane only, 4.6 KB
    __shared__ float Xb[2][BTILE][65];                   // 4.2 KB
    __shared__ __align__(16) f32x4 Pbuf[2][8][8];        // [step&1][pslot][batch] 2 KB

    for (int i = tid; i < 2 * 16 * HS; i += 320)
        reinterpret_cast<unsigned*>(Hbuf)[i] = 0u;

    // ---- L1 A-fragments (waves 0..3): a1[g][kt] = W_hh0 tile (w8+4g, kt) ----
    short8 a1[4][2];
    f32x2 wg2[4], bg2[4];
    float w1A[4], w1B[4];
    if (w8 < 4) {
        #pragma unroll
        for (int g = 0; g < 4; ++g) {
            #pragma unroll
            for (int kt = 0; kt < 2; ++kt) {
                const float* p = W_hh0 + (size_t)(16 * (w8 + 4 * g) + n16) * 64 + kt * 32 + q16 * 8;
                short8 a;
                #pragma unroll
                for (int j = 0; j < 8; ++j) a[j] = (short)f2bf(p[j]);
                a1[g][kt] = a;
            }
        }
        #pragma unroll
        for (int g = 0; g < 4; ++g) {
            int rA = g * 64 + ua;
            int rB = rA + 1;
            wg2[g] = f32x2{W_ih0[rA], W_ih0[rB]};
            bg2[g] = f32x2{b_ih0[rA] + b_hh0[rA], b_ih0[rB] + b_hh0[rB]};
            w1A[g] = W_ih1[g * 64 + ua];
            w1B[g] = W_ih1[g * 64 + ua + 1];
        }
    }
    float wh1[4], bb1[4];
    #pragma unroll
    for (int g = 0; g < 4; ++g) { wh1[g] = W_hh1[g]; bb1[g] = b_ih1[g] + b_hh1[g]; }

    // ---- input staging: tid<256, thread (xr, xc) covers rows 0..7 x cols 0..63 ----
    const int xr = (tid >> 5) & 7;
    const int xc = tid & 31;
    const float* rowptr = input + (size_t)(bbase + xr) * T_STEPS;
    if (tid < 256) {
        Xb[0][xr][xc]      = rowptr[xc];
        Xb[0][xr][xc + 32] = rowptr[xc + 32];
    }
    float xnA = 0.0f, xnB = 0.0f;
    f32x2 c02 = {0.0f, 0.0f};
    float h1 = 0.0f, c1 = 0.0f;
    float pgc[4] = {0.0f, 0.0f, 0.0f, 0.0f};   // step-(t-1) pre-reduce partials

    __syncthreads();

    int par = 0;
    #pragma unroll 2
    for (int t = 0; t < T_STEPS; ++t) {
        if (w8 < 4) {
            if ((t & 63) == 0 && t + 64 < T_STEPS) {
                xnA = rowptr[t + 64 + xc];
                xnB = rowptr[t + 64 + xc + 32];
            }
            const int cp = (t >> 6) & 1;

            // ---- B-fragments: h(t-1) ----
            const unsigned* Hrow = &Hbuf[par][n16][0];
            short8 hb0 = *reinterpret_cast<const short8*>(Hrow + 4 * q16);
            short8 hb1 = *reinterpret_cast<const short8*>(Hrow + 16 + 4 * q16);

            // ---- L1 MFMA ----
            f32x4 accv[4];
            #pragma unroll
            for (int g = 0; g < 4; ++g) {
                f32x4 z = {0.0f, 0.0f, 0.0f, 0.0f};
                z = __builtin_amdgcn_mfma_f32_16x16x32_bf16(a1[g][0], hb0, z, 0, 0, 0);
                z = __builtin_amdgcn_mfma_f32_16x16x32_bf16(a1[g][1], hb1, z, 0, 0, 0);
                accv[g] = z;
            }

            // ---- DEFERRED reduce of step t-1 partials (hides under MFMA) ----
            if (t > 0) {
                #pragma unroll
                for (int g = 0; g < 4; ++g) {
                    float s = pgc[g] + dpp_xor8(pgc[g]);                         // xor 8 (VALU)
                    s = s + __int_as_float(
                        __builtin_amdgcn_ds_swizzle(__float_as_int(s), 0x401F)); // xor 16
                    pgc[g] = s;
                }
                if ((l & 31) < 8) {
                    const int pslot = 2 * w8 + (l >> 5);
                    Pbuf[(t - 1) & 1][pslot][n8] = f32x4{pgc[0], pgc[1], pgc[2], pgc[3]};
                }
            }

            // ---- gate select (8 DPP serve the 2 cells) ----
            float vA[4], vB[4];
            #pragma unroll
            for (int g = 0; g < 4; ++g) {
                int pa = __float_as_int(accv[g][0]);
                pa = __builtin_amdgcn_update_dpp(pa, __float_as_int(accv[g][2]), 0x118, 0xf, 0xC, false);
                int pb = __float_as_int(accv[g][1]);
                pb = __builtin_amdgcn_update_dpp(pb, __float_as_int(accv[g][3]), 0x118, 0xf, 0xC, false);
                vA[g] = __int_as_float(pa);
                vB[g] = __int_as_float(pb);
            }

            // ---- layer-1 activation, 2 cells (batch n8, units ua/ua+1) ----
            float x = Xb[cp][n8][t & 63];
            f32x2 xx = {x, x};
            f32x2 gi = f32x2{vA[0], vB[0]} + (xx * wg2[0] + bg2[0]);
            f32x2 gf = f32x2{vA[1], vB[1]} + (xx * wg2[1] + bg2[1]);
            f32x2 gg = f32x2{vA[2], vB[2]} + (xx * wg2[2] + bg2[2]);
            f32x2 go = f32x2{vA[3], vB[3]} + (xx * wg2[3] + bg2[3]);

            f32x2 si = sigf2(gi);
            f32x2 sf = sigf2(gf);
            f32x2 tg = tanh2(gg);
            f32x2 c0n2 = sf * c02 + si * tg;
            c02 = c0n2;
            f32x2 so = sigf2(go);
            f32x2 th = tanh2(c0n2);
            f32x2 h0n2 = so * th;

            // ---- h pack + write (loop-carried) ----
            const int widx = 8 * w8 + 2 * q16 + hi8;
            Hbuf[par ^ 1][n8][widx] = cvt_pk_bf16(h0n2[0], h0n2[1]);

            // ---- L2 gate partial FMAs only; reduce deferred to next iter ----
            #pragma unroll
            for (int g = 0; g < 4; ++g)
                pgc[g] = w1A[g] * c0n2[0] + w1B[g] * c0n2[1];

            if ((t & 63) == 63 && t + 1 < T_STEPS) {
                Xb[cp ^ 1][xr][xc]      = xnA;
                Xb[cp ^ 1][xr][xc + 32] = xnB;
            }
        } else {
            // ---- wave 4: L2 recurrence for step t-2 (8 independent lanes) ----
            if (t > 1 && l < 8) {
                f32x4 s = Pbuf[t & 1][0][l];
                #pragma unroll
                for (int p = 1; p < 8; ++p) s += Pbuf[t & 1][p][l];
                float gi = s[0] + bb1[0] + h1 * wh1[0];
                float gf = s[1] + bb1[1] + h1 * wh1[1];
                float gg = s[2] + bb1[2] + h1 * wh1[2];
                float go = s[3] + bb1[3] + h1 * wh1[3];
                float c1n = sigf(gf) * c1 + sigf(gi) * tanh_fast(gg);
                c1 = c1n;
                h1 = sigf(go) * tanh_fast(c1n);
                out[(size_t)(bbase + l) * T_STEPS + (t - 2)] = c1n;
            }
        }

        step_barrier();
        par ^= 1;
    }

    // ---- epilogue 1: L1 waves reduce + write step-1023 partials (parity 1) ----
    if (w8 < 4) {
        #pragma unroll
        for (int g = 0; g < 4; ++g) {
            float s = pgc[g] + dpp_xor8(pgc[g]);
            s = s + __int_as_float(
                __builtin_amdgcn_ds_swizzle(__float_as_int(s), 0x401F));
            pgc[g] = s;
        }
        if ((l & 31) < 8) {
            const int pslot = 2 * w8 + (l >> 5);
            Pbuf[1][pslot][n8] = f32x4{pgc[0], pgc[1], pgc[2], pgc[3]};
        }
    }
    step_barrier();

    // ---- epilogue 2: wave 4 flushes steps 1022 (parity 0) and 1023 (parity 1) ----
    if (w8 == 4 && l < 8) {
        {
            f32x4 s = Pbuf[0][0][l];
            #pragma unroll
            for (int p = 1; p < 8; ++p) s += Pbuf[0][p][l];
            float gi = s[0] + bb1[0] + h1 * wh1[0];
            float gf = s[1] + bb1[1] + h1 * wh1[1];
            float gg = s[2] + bb1[2] + h1 * wh1[2];
            float go = s[3] + bb1[3] + h1 * wh1[3];
            float c1n = sigf(gf) * c1 + sigf(gi) * tanh_fast(gg);
            c1 = c1n;
            h1 = sigf(go) * tanh_fast(c1n);
            out[(size_t)(bbase + l) * T_STEPS + (T_STEPS - 2)] = c1n;
        }
        {
            f32x4 s = Pbuf[1][0][l];
            #pragma unroll
            for (int p = 1; p < 8; ++p) s += Pbuf[1][p][l];
            float gi = s[0] + bb1[0] + h1 * wh1[0];
            float gf = s[1] + bb1[1] + h1 * wh1[1];
            float gg = s[2] + bb1[2] + h1 * wh1[2];
            float c1n = sigf(gf) * c1 + sigf(gi) * tanh_fast(gg);
            out[(size_t)(bbase + l) * T_STEPS + (T_STEPS - 1)] = c1n;
        }
    }
}

extern "C" void kernel_launch(void* const* d_in, const int* in_sizes, int n_in,
                              void* d_out, int out_size, void* d_ws, size_t ws_size,
                              hipStream_t stream) {
    const float* input = (const float*)d_in[0];
    const float* W_ih0 = (const float*)d_in[1];
    const float* W_hh0 = (const float*)d_in[2];
    const float* b_ih0 = (const float*)d_in[3];
    const float* b_hh0 = (const float*)d_in[4];
    const float* W_ih1 = (const float*)d_in[5];
    const float* W_hh1 = (const float*)d_in[6];
    const float* b_ih1 = (const float*)d_in[7];
    const float* b_hh1 = (const float*)d_in[8];
    float* out = (float*)d_out;

    lstm_v15_kernel<<<dim3(BATCH / BTILE), dim3(320), 0, stream>>>(
        input, W_ih0, W_hh0, b_ih0, b_hh0, W_ih1, W_hh1, b_ih1, b_hh1, out);
}

// Round 8
// 474.375 us; speedup vs baseline: 1.1642x; 1.1642x over previous
//
#include <hip/hip_runtime.h>

#define T_STEPS 1024
#define BATCH 2048
#define BTILE 8   // 8 batch rows/block -> 256 blocks -> 1 block/CU
#define HS 36     // LDS row stride in u32 words; 36 % 32 == 4 -> conflict-free b128 reads

typedef short short8 __attribute__((ext_vector_type(8)));
typedef float f32x4 __attribute__((ext_vector_type(4)));
typedef float f32x2 __attribute__((ext_vector_type(2)));

__device__ __forceinline__ float fast_rcp(float x) {
#if __has_builtin(__builtin_amdgcn_rcpf)
    return __builtin_amdgcn_rcpf(x);
#else
    return 1.0f / x;
#endif
}

__device__ __forceinline__ float fast_exp2(float x) {
#if __has_builtin(__builtin_amdgcn_exp2f)
    return __builtin_amdgcn_exp2f(x);
#else
    return exp2f(x);
#endif
}

__device__ __forceinline__ float sigf(float x) {
    return fast_rcp(1.0f + fast_exp2(-1.44269504f * x));
}

__device__ __forceinline__ f32x2 sigf2(f32x2 v) {
    f32x2 t = v * (-1.44269504f);
    f32x2 e = {fast_exp2(t[0]), fast_exp2(t[1])};
    e = e + 1.0f;
    return f32x2{fast_rcp(e[0]), fast_rcp(e[1])};
}

__device__ __forceinline__ float tanh_fast(float x) {
    float e = fast_exp2(2.88539008f * x);
    return 1.0f - 2.0f * fast_rcp(e + 1.0f);
}

__device__ __forceinline__ f32x2 tanh2(f32x2 v) {
    f32x2 t = v * 2.88539008f;
    f32x2 e = {fast_exp2(t[0]), fast_exp2(t[1])};
    e = e + 1.0f;
    f32x2 r = {fast_rcp(e[0]), fast_rcp(e[1])};
    return f32x2{1.0f, 1.0f} - 2.0f * r;
}

// float -> bf16 bits (RNE) — setup only
__device__ __forceinline__ unsigned f2bf(float x) {
    unsigned u = __float_as_uint(x);
    unsigned r = u + 0x7FFFu + ((u >> 16) & 1u);
    return r >> 16;
}
__device__ __forceinline__ float bf2f(unsigned b) {
    return __uint_as_float(b << 16);
}

__device__ __forceinline__ unsigned cvt_pk_bf16(float a, float b) {
    unsigned r;
    asm("v_cvt_pk_bf16_f32 %0, %1, %2" : "=v"(r) : "v"(a), "v"(b));
    return r;
}

// Per-step barrier without the vmcnt(0) drain __syncthreads() emits.
// All in-loop cross-wave traffic is LDS (lgkmcnt(0)+s_barrier orders it);
// global ops are write-only stores / same-thread prefetch.
__device__ __forceinline__ void step_barrier() {
    asm volatile("s_waitcnt lgkmcnt(0)\n\ts_barrier" ::: "memory");
}

// ===================== v16: L2 GEMV on dedicated wave 4 =====================
// v14's remaining chain tail: after c0n2, compute waves ran 4 FMAs + two
// serial ds_swizzles (xor8/xor16, ~2 LDS round-trips) + Pbuf write — all on
// the barrier chain every step. v16 moves the L2 GEMV back to MFMA form
// (v12's hi/lo bf16 split, identical math) but on the DEDICATED wave 4:
// unlike v12's rotating duty wave (which skewed a compute wave every step),
// wave 4 has a whole step of slack (4 ds_reads + 6 MFMAs + 8-lane serial
// recurrence ~500cy < step). Compute waves now just pack h + c-hi/lo (3
// ds_writes); no swizzle reduce, no Pbuf, no L2 FMAs on their chain.
__global__ __launch_bounds__(320, 1)
void lstm_v16_kernel(const float* __restrict__ input,
                     const float* __restrict__ W_ih0,
                     const float* __restrict__ W_hh0,
                     const float* __restrict__ b_ih0,
                     const float* __restrict__ b_hh0,
                     const float* __restrict__ W_ih1,
                     const float* __restrict__ W_hh1,
                     const float* __restrict__ b_ih1,
                     const float* __restrict__ b_hh1,
                     float* __restrict__ out)
{
    const int tid = threadIdx.x;
    const int w8  = tid >> 6;        // wave 0..3 = L1 compute, wave 4 = L2
    const int l   = tid & 63;
    const int q16 = l >> 4;
    const int n16 = l & 15;
    const int n8  = l & 7;           // batch within block
    const int hi8 = n16 >> 3;
    const int ua  = 16 * w8 + 4 * q16 + 2 * hi8;   // even unit of pair (w8<4)
    const int bbase = blockIdx.x * BTILE;

    __shared__ __align__(16) unsigned Hbuf[2][3][16][HS];   // h, c_hi, c_lo planes
    __shared__ float Xb[2][BTILE][65];                      // 4.2 KB

    for (int i = tid; i < 2 * 3 * 16 * HS; i += 320)
        reinterpret_cast<unsigned*>(Hbuf)[i] = 0u;

    // ---- compute-wave constants ----
    short8 a1[4][2];
    f32x2 wg2[4], bg2[4];
    if (w8 < 4) {
        #pragma unroll
        for (int g = 0; g < 4; ++g) {
            #pragma unroll
            for (int kt = 0; kt < 2; ++kt) {
                const float* p = W_hh0 + (size_t)(16 * (w8 + 4 * g) + n16) * 64 + kt * 32 + q16 * 8;
                short8 a;
                #pragma unroll
                for (int j = 0; j < 8; ++j) a[j] = (short)f2bf(p[j]);
                a1[g][kt] = a;
            }
        }
        #pragma unroll
        for (int g = 0; g < 4; ++g) {
            int rA = g * 64 + ua;
            int rB = rA + 1;
            wg2[g] = f32x2{W_ih0[rA], W_ih0[rB]};
            bg2[g] = f32x2{b_ih0[rA] + b_hh0[rA], b_ih0[rB] + b_hh0[rB]};
        }
    }

    // ---- wave-4 constants: L2 A-fragments (hi/lo split) + recurrence ----
    short8 a2h[2], a2l[2];
    float wh1[4], bb1[4];
    if (w8 == 4) {
        #pragma unroll
        for (int kt = 0; kt < 2; ++kt) {
            short8 ah = {0,0,0,0,0,0,0,0}, al = {0,0,0,0,0,0,0,0};
            if (n16 < 4) {
                const float* p = W_ih1 + (size_t)n16 * 64 + kt * 32 + q16 * 8;
                #pragma unroll
                for (int j = 0; j < 8; ++j) {
                    unsigned hb = f2bf(p[j]);
                    ah[j] = (short)hb;
                    al[j] = (short)f2bf(p[j] - bf2f(hb));
                }
            }
            a2h[kt] = ah; a2l[kt] = al;
        }
        #pragma unroll
        for (int g = 0; g < 4; ++g) { wh1[g] = W_hh1[g]; bb1[g] = b_ih1[g] + b_hh1[g]; }
    }

    // ---- input staging: tid<256, thread (xr, xc) covers rows 0..7 x cols 0..63 ----
    const int xr = (tid >> 5) & 7;
    const int xc = tid & 31;
    const float* rowptr = input + (size_t)(bbase + xr) * T_STEPS;
    if (tid < 256) {
        Xb[0][xr][xc]      = rowptr[xc];
        Xb[0][xr][xc + 32] = rowptr[xc + 32];
    }
    float xnA = 0.0f, xnB = 0.0f;
    f32x2 c02 = {0.0f, 0.0f};
    float h1 = 0.0f, c1 = 0.0f;      // wave-4 L2 state (lanes 0..7)

    __syncthreads();

    int par = 0;
    #pragma unroll 2
    for (int t = 0; t < T_STEPS; ++t) {
        if (w8 < 4) {
            if ((t & 63) == 0 && t + 64 < T_STEPS) {
                xnA = rowptr[t + 64 + xc];
                xnB = rowptr[t + 64 + xc + 32];
            }
            const int cp = (t >> 6) & 1;

            // ---- B-fragments: h(t-1) ----
            const unsigned* Hrow = &Hbuf[par][0][n16][0];
            short8 hb0 = *reinterpret_cast<const short8*>(Hrow + 4 * q16);
            short8 hb1 = *reinterpret_cast<const short8*>(Hrow + 16 + 4 * q16);

            // ---- L1 MFMA ----
            f32x4 accv[4];
            #pragma unroll
            for (int g = 0; g < 4; ++g) {
                f32x4 z = {0.0f, 0.0f, 0.0f, 0.0f};
                z = __builtin_amdgcn_mfma_f32_16x16x32_bf16(a1[g][0], hb0, z, 0, 0, 0);
                z = __builtin_amdgcn_mfma_f32_16x16x32_bf16(a1[g][1], hb1, z, 0, 0, 0);
                accv[g] = z;
            }

            // ---- gate select (8 DPP serve the 2 cells) ----
            float vA[4], vB[4];
            #pragma unroll
            for (int g = 0; g < 4; ++g) {
                int pa = __float_as_int(accv[g][0]);
                pa = __builtin_amdgcn_update_dpp(pa, __float_as_int(accv[g][2]), 0x118, 0xf, 0xC, false);
                int pb = __float_as_int(accv[g][1]);
                pb = __builtin_amdgcn_update_dpp(pb, __float_as_int(accv[g][3]), 0x118, 0xf, 0xC, false);
                vA[g] = __int_as_float(pa);
                vB[g] = __int_as_float(pb);
            }

            // ---- layer-1 activation, 2 cells (batch n8, units ua/ua+1) ----
            float x = Xb[cp][n8][t & 63];
            f32x2 xx = {x, x};
            f32x2 gi = f32x2{vA[0], vB[0]} + (xx * wg2[0] + bg2[0]);
            f32x2 gf = f32x2{vA[1], vB[1]} + (xx * wg2[1] + bg2[1]);
            f32x2 gg = f32x2{vA[2], vB[2]} + (xx * wg2[2] + bg2[2]);
            f32x2 go = f32x2{vA[3], vB[3]} + (xx * wg2[3] + bg2[3]);

            f32x2 si = sigf2(gi);
            f32x2 sf = sigf2(gf);
            f32x2 tg = tanh2(gg);
            f32x2 c0n2 = sf * c02 + si * tg;
            c02 = c0n2;
            f32x2 so = sigf2(go);
            f32x2 th = tanh2(c0n2);
            f32x2 h0n2 = so * th;

            // ---- pack h + c hi/lo (in-thread pairs), 3 ds_writes ----
            const int widx = 8 * w8 + 2 * q16 + hi8;
            unsigned hword  = cvt_pk_bf16(h0n2[0], h0n2[1]);
            Hbuf[par ^ 1][0][n8][widx] = hword;
            unsigned chword = cvt_pk_bf16(c0n2[0], c0n2[1]);
            float hiA = bf2f(chword & 0xFFFFu);
            float hiB = bf2f(chword >> 16);
            f32x2 lo = c0n2 - f32x2{hiA, hiB};
            unsigned clword = cvt_pk_bf16(lo[0], lo[1]);
            Hbuf[par ^ 1][1][n8][widx] = chword;
            Hbuf[par ^ 1][2][n8][widx] = clword;

            if ((t & 63) == 63 && t + 1 < T_STEPS) {
                Xb[cp ^ 1][xr][xc]      = xnA;
                Xb[cp ^ 1][xr][xc + 32] = xnB;
            }
        } else {
            // ---- wave 4: L2 GEMV (6 MFMA, hi/lo) + recurrence for step t-1 ----
            if (t > 0) {
                const unsigned* Ch = &Hbuf[par][1][n16][0];
                const unsigned* Cl = &Hbuf[par][2][n16][0];
                short8 ch0 = *reinterpret_cast<const short8*>(Ch + 4 * q16);
                short8 ch1 = *reinterpret_cast<const short8*>(Ch + 16 + 4 * q16);
                short8 cl0 = *reinterpret_cast<const short8*>(Cl + 4 * q16);
                short8 cl1 = *reinterpret_cast<const short8*>(Cl + 16 + 4 * q16);
                f32x4 zA = {0.0f, 0.0f, 0.0f, 0.0f};
                f32x4 zB = {0.0f, 0.0f, 0.0f, 0.0f};
                zA = __builtin_amdgcn_mfma_f32_16x16x32_bf16(a2h[0], ch0, zA, 0, 0, 0);
                zB = __builtin_amdgcn_mfma_f32_16x16x32_bf16(a2l[1], ch1, zB, 0, 0, 0);
                zA = __builtin_amdgcn_mfma_f32_16x16x32_bf16(a2h[1], ch1, zA, 0, 0, 0);
                zB = __builtin_amdgcn_mfma_f32_16x16x32_bf16(a2h[0], cl0, zB, 0, 0, 0);
                zA = __builtin_amdgcn_mfma_f32_16x16x32_bf16(a2l[0], ch0, zA, 0, 0, 0);
                zB = __builtin_amdgcn_mfma_f32_16x16x32_bf16(a2h[1], cl1, zB, 0, 0, 0);
                f32x4 z = zA + zB;
                if (l < 8) {
                    float gi = z[0] + bb1[0] + h1 * wh1[0];
                    float gf = z[1] + bb1[1] + h1 * wh1[1];
                    float gg = z[2] + bb1[2] + h1 * wh1[2];
                    float go = z[3] + bb1[3] + h1 * wh1[3];
                    float c1n = sigf(gf) * c1 + sigf(gi) * tanh_fast(gg);
                    c1 = c1n;
                    h1 = sigf(go) * tanh_fast(c1n);
                    out[(size_t)(bbase + l) * T_STEPS + (t - 1)] = c1n;
                }
            }
        }

        step_barrier();
        par ^= 1;
    }

    // ---- epilogue: wave 4 processes step 1023 (Hbuf[par] = step-1023 data) ----
    if (w8 == 4) {
        const unsigned* Ch = &Hbuf[par][1][n16][0];
        const unsigned* Cl = &Hbuf[par][2][n16][0];
        short8 ch0 = *reinterpret_cast<const short8*>(Ch + 4 * q16);
        short8 ch1 = *reinterpret_cast<const short8*>(Ch + 16 + 4 * q16);
        short8 cl0 = *reinterpret_cast<const short8*>(Cl + 4 * q16);
        short8 cl1 = *reinterpret_cast<const short8*>(Cl + 16 + 4 * q16);
        f32x4 zA = {0.0f, 0.0f, 0.0f, 0.0f};
        f32x4 zB = {0.0f, 0.0f, 0.0f, 0.0f};
        zA = __builtin_amdgcn_mfma_f32_16x16x32_bf16(a2h[0], ch0, zA, 0, 0, 0);
        zB = __builtin_amdgcn_mfma_f32_16x16x32_bf16(a2l[1], ch1, zB, 0, 0, 0);
        zA = __builtin_amdgcn_mfma_f32_16x16x32_bf16(a2h[1], ch1, zA, 0, 0, 0);
        zB = __builtin_amdgcn_mfma_f32_16x16x32_bf16(a2h[0], cl0, zB, 0, 0, 0);
        zA = __builtin_amdgcn_mfma_f32_16x16x32_bf16(a2l[0], ch0, zA, 0, 0, 0);
        zB = __builtin_amdgcn_mfma_f32_16x16x32_bf16(a2h[1], cl1, zB, 0, 0, 0);
        f32x4 z = zA + zB;
        if (l < 8) {
            float gi = z[0] + bb1[0] + h1 * wh1[0];
            float gf = z[1] + bb1[1] + h1 * wh1[1];
            float gg = z[2] + bb1[2] + h1 * wh1[2];
            float c1n = sigf(gf) * c1 + sigf(gi) * tanh_fast(gg);
            out[(size_t)(bbase + l) * T_STEPS + (T_STEPS - 1)] = c1n;
        }
    }
}

extern "C" void kernel_launch(void* const* d_in, const int* in_sizes, int n_in,
                              void* d_out, int out_size, void* d_ws, size_t ws_size,
                              hipStream_t stream) {
    const float* input = (const float*)d_in[0];
    const float* W_ih0 = (const float*)d_in[1];
    const float* W_hh0 = (const float*)d_in[2];
    const float* b_ih0 = (const float*)d_in[3];
    const float* b_hh0 = (const float*)d_in[4];
    const float* W_ih1 = (const float*)d_in[5];
    const float* W_hh1 = (const float*)d_in[6];
    const float* b_ih1 = (const float*)d_in[7];
    const float* b_hh1 = (const float*)d_in[8];
    float* out = (float*)d_out;

    lstm_v16_kernel<<<dim3(BATCH / BTILE), dim3(320), 0, stream>>>(
        input, W_ih0, W_hh0, b_ih0, b_hh0, W_ih1, W_hh1, b_ih1, b_hh1, out);
}